// Round 14
// baseline (772.973 us; speedup 1.0000x reference)
//
#include <hip/hip_runtime.h>

typedef unsigned short ushort_t;
typedef unsigned int uint_t;
typedef _Float16 f16_t;
typedef _Float16 half2_t __attribute__((ext_vector_type(2)));
typedef _Float16 half8_t __attribute__((ext_vector_type(8)));
typedef float floatx4 __attribute__((ext_vector_type(4)));
typedef unsigned int uintx4 __attribute__((ext_vector_type(4)));

__device__ __forceinline__ ushort_t f2h_bits(float f) {
    f16_t h = (f16_t)f;
    return __builtin_bit_cast(ushort_t, h);
}
__device__ __forceinline__ float h2f(ushort_t u) {
    return (float)__builtin_bit_cast(f16_t, u);
}
__device__ __forceinline__ float h2f_lo(uint_t u) { return h2f((ushort_t)(u & 0xFFFF)); }
__device__ __forceinline__ float h2f_hi(uint_t u) { return h2f((ushort_t)(u >> 16)); }
__device__ __forceinline__ float sigm(float x) { return 1.0f / (1.0f + __expf(-x)); }
__device__ __forceinline__ float tanhx(float x) {
    x = fminf(fmaxf(x, -15.0f), 15.0f);
    float e = __expf(2.0f * x);
    return (e - 1.0f) / (e + 1.0f);
}
__device__ __forceinline__ half8_t h8(uint4 v) { return __builtin_bit_cast(half8_t, v); }
__device__ __forceinline__ half8_t h8x(uintx4 v) { return __builtin_bit_cast(half8_t, v); }

// B-fragment layout everywhere: frag(kt,q,n) at halves ((kt*4+q)*V + n)*8 + j,
// holding B[k][n] with k = kt*32 + q*8 + j. Consecutive n -> contiguous b128.
__device__ __forceinline__ half8_t ldfrag(const ushort_t* p, int V, int kt, int q, int n) {
    return *(const half8_t*)(p + ((size_t)((kt * 4 + q) * V + n)) * 8);
}

__device__ __forceinline__ void pack_one(
    const float* srcA, int KA, const float* srcB, int KB,
    ushort_t* dst, int V, int K, int idx)
{
    int v = idx / K, k = idx - v * K;
    float val = 0.0f;
    if (k < KA) val = srcA[v * KA + k];
    else if (k < KA + KB) val = srcB[v * KB + (k - KA)];
    int kt = k >> 5, qq = (k >> 3) & 3, j = k & 7;
    dst[((size_t)((kt * 4 + qq) * V + v)) * 8 + j] = f2h_bits(val);
}

// t-LSTM variant: V=768, skip dead f-gate rows (src row = v<256 ? v : v+256).
__device__ __forceinline__ void pack_tl_one(
    const float* src, int Ksrc, ushort_t* dst, int K, int idx)
{
    int v = idx / K, k = idx - v * K;
    int r = (v < 256) ? v : v + 256;
    float val = (k < Ksrc) ? src[r * Ksrc + k] : 0.0f;
    int kt = k >> 5, qq = (k >> 3) & 3, j = k & 7;
    dst[((size_t)((kt * 4 + qq) * 768 + v)) * 8 + j] = f2h_bits(val);
}

// All 5 weight packs + flag zeroing in one launch.
__global__ __launch_bounds__(256) void packAll(
    const float* __restrict__ tWih0, const float* __restrict__ tWih1,
    const float* __restrict__ nWih0, const float* __restrict__ nWhh0,
    const float* __restrict__ nWih1, const float* __restrict__ nWhh1,
    ushort_t* __restrict__ W0m, ushort_t* __restrict__ W1m,
    ushort_t* __restrict__ N0x, ushort_t* __restrict__ N0m,
    ushort_t* __restrict__ N1m, uint_t* __restrict__ flags)
{
    int idx = blockIdx.x * 256 + threadIdx.x;
    if (idx < 49152) { pack_tl_one(tWih0, 50, W0m, 64, idx); return; }
    idx -= 49152;
    if (idx < 196608) { pack_tl_one(tWih1, 256, W1m, 256, idx); return; }
    idx -= 196608;
    if (idx < 131072) { pack_one(nWih0, 257, (const float*)0, 0, N0x, 512, 256, idx); return; }
    idx -= 131072;
    if (idx < 65536) { pack_one(nWhh0, 128, (const float*)0, 0, N0m, 512, 128, idx); return; }
    idx -= 65536;
    if (idx < 131072) { pack_one(nWih1, 128, nWhh1, 128, N1m, 512, 256, idx); return; }
    idx -= 131072;
    if (idx < 1536) flags[idx] = 0;
}

// mega: producer/consumer fusion.
//  blocks 0..1535  : fusedA t-major tiles (t = blk>>5, 32 batches each);
//                    after G1 stores: fence + release atomicAdd(flags[t*32]).
//  blocks 1536..1599: phaseB (16 batches each); spin-acquire on flags[t*32]==32
//                    before consuming G1[t]. Whh0 B-frags register-resident
//                    (16/thread, fixed (q,u) slice) so both roles share a
//                    36.9 kB dynamic-LDS footprint.
__global__ __launch_bounds__(512) __attribute__((amdgpu_waves_per_eu(2)))
void mega(
    const float* __restrict__ note, const float* __restrict__ targets,
    const ushort_t* __restrict__ W0m, const float* __restrict__ b0,
    const ushort_t* __restrict__ W1m, const float* __restrict__ b1,
    const ushort_t* __restrict__ N0x, const float* __restrict__ nWih0raw,
    const float* __restrict__ nb0,
    const ushort_t* __restrict__ N0m, const ushort_t* __restrict__ N1m,
    const float* __restrict__ nb1,
    const float* __restrict__ outW, const float* __restrict__ outb,
    uint_t* __restrict__ G1u, uint_t* __restrict__ flags,
    float* __restrict__ out)
{
    extern __shared__ __align__(16) char smem[];
    const int tid = threadIdx.x;
    const int wv = tid >> 6, l = tid & 63, l16 = l & 15, q = l >> 4;

    if (blockIdx.x < 1536) {
        // ================= producer: fusedA (t-major) =================
        ushort_t* xAa = (ushort_t*)smem;             // 32*64
        ushort_t* xH1 = (ushort_t*)(smem + 4096);    // 32*256
        ushort_t* xH2 = (ushort_t*)(smem + 20480);   // 32*256
        const int tt  = blockIdx.x >> 5;
        const int b0r = (blockIdx.x & 31) * 32;

        // staging: features for 32 batches at time tt (K padded 56->64)
        for (int idx = tid; idx < 32 * 64; idx += 512) {
            int r = idx >> 6, c = idx & 63;
            int b = b0r + r;
            float val = 0.0f;
            if (c == 0) val = (float)tt * (1.0f / 48.0f);
            else if (c < 13) val = ((tt % 12) == (c - 1)) ? 1.0f : 0.0f;
            else if (c < 38) {
                int p = tt + (c - 13) - 12;
                if (p >= 0 && p < 48) val = note[b * 48 + p];
            } else if (c < 50) {
                const float* nb = note + b * 48 + (c - 38) * 4;
                val = nb[0] + nb[1] + nb[2] + nb[3];
            }
            int kb = c >> 3, j = c & 7;
            xAa[r * 64 + (((kb ^ r) & 7) << 3) + j] = f2h_bits(val);
        }
        __syncthreads();

        // ---- GEMM1 (K=64) + gate -> xH1 ----
#pragma unroll
        for (int s = 0; s < 2; ++s) {
            const int u = (wv * 2 + s) * 16 + l16;
            floatx4 acc[2][3] = {};
#pragma unroll
            for (int kt = 0; kt < 2; ++kt) {
                half8_t bI = ldfrag(W0m, 768, kt, q, u);
                half8_t bG = ldfrag(W0m, 768, kt, q, 256 + u);
                half8_t bO = ldfrag(W0m, 768, kt, q, 512 + u);
                int kbp = ((kt * 4 + q) ^ l16) & 7;
#pragma unroll
                for (int mt = 0; mt < 2; ++mt) {
                    half8_t a = *(const half8_t*)&xAa[(mt * 16 + l16) * 64 + kbp * 8];
                    acc[mt][0] = __builtin_amdgcn_mfma_f32_16x16x32_f16(a, bI, acc[mt][0], 0, 0, 0);
                    acc[mt][1] = __builtin_amdgcn_mfma_f32_16x16x32_f16(a, bG, acc[mt][1], 0, 0, 0);
                    acc[mt][2] = __builtin_amdgcn_mfma_f32_16x16x32_f16(a, bO, acc[mt][2], 0, 0, 0);
                }
            }
            float bi = b0[u], bg = b0[512 + u], bo = b0[768 + u];
            int kbW = u >> 3;
#pragma unroll
            for (int mt = 0; mt < 2; ++mt)
#pragma unroll
                for (int r = 0; r < 4; ++r) {
                    float c = sigm(acc[mt][0][r] + bi) * tanhx(acc[mt][1][r] + bg);
                    float h = sigm(acc[mt][2][r] + bo) * tanhx(c);
                    int m = mt * 16 + q * 4 + r;
                    int kbp = (kbW & 16) | ((kbW ^ (m & 15)) & 15);
                    xH1[m * 256 + kbp * 8 + (u & 7)] = f2h_bits(h);
                }
        }
        __syncthreads();

        // ---- GEMM2 (K=256) + gate -> xH2 ----
#pragma unroll
        for (int s = 0; s < 2; ++s) {
            const int u = (wv * 2 + s) * 16 + l16;
            floatx4 acc[2][3] = {};
#pragma unroll
            for (int kt = 0; kt < 8; ++kt) {
                half8_t bI = ldfrag(W1m, 768, kt, q, u);
                half8_t bG = ldfrag(W1m, 768, kt, q, 256 + u);
                half8_t bO = ldfrag(W1m, 768, kt, q, 512 + u);
                int kb = kt * 4 + q;
                int kbp = (kb & 16) | ((kb ^ l16) & 15);
#pragma unroll
                for (int mt = 0; mt < 2; ++mt) {
                    half8_t a = *(const half8_t*)&xH1[(mt * 16 + l16) * 256 + kbp * 8];
                    acc[mt][0] = __builtin_amdgcn_mfma_f32_16x16x32_f16(a, bI, acc[mt][0], 0, 0, 0);
                    acc[mt][1] = __builtin_amdgcn_mfma_f32_16x16x32_f16(a, bG, acc[mt][1], 0, 0, 0);
                    acc[mt][2] = __builtin_amdgcn_mfma_f32_16x16x32_f16(a, bO, acc[mt][2], 0, 0, 0);
                }
            }
            float bi = b1[u], bg = b1[512 + u], bo = b1[768 + u];
            int kbW = u >> 3;
#pragma unroll
            for (int mt = 0; mt < 2; ++mt)
#pragma unroll
                for (int r = 0; r < 4; ++r) {
                    float c = sigm(acc[mt][0][r] + bi) * tanhx(acc[mt][1][r] + bg);
                    float h = sigm(acc[mt][2][r] + bo) * tanhx(c);
                    int m = mt * 16 + q * 4 + r;
                    int kbp = (kbW & 16) | ((kbW ^ (m & 15)) & 15);
                    xH2[m * 256 + kbp * 8 + (u & 7)] = f2h_bits(h);
                }
        }
        __syncthreads();

        // ---- GEMM3 (K=256) + bias + cond rank-1 -> G1 ----
        {
            const int u2 = wv * 16 + l16;
            floatx4 acc[2][4] = {};
#pragma unroll
            for (int kt = 0; kt < 8; ++kt) {
                half8_t bf[4];
#pragma unroll
                for (int g = 0; g < 4; ++g) bf[g] = ldfrag(N0x, 512, kt, q, g * 128 + u2);
                int kb = kt * 4 + q;
                int kbp = (kb & 16) | ((kb ^ l16) & 15);
#pragma unroll
                for (int mt = 0; mt < 2; ++mt) {
                    half8_t a = *(const half8_t*)&xH2[(mt * 16 + l16) * 256 + kbp * 8];
#pragma unroll
                    for (int g = 0; g < 4; ++g)
                        acc[mt][g] = __builtin_amdgcn_mfma_f32_16x16x32_f16(a, bf[g], acc[mt][g], 0, 0, 0);
                }
            }
            float bias[4], wc[4];
#pragma unroll
            for (int g = 0; g < 4; ++g) {
                bias[g] = nb0[g * 128 + u2];
                wc[g] = nWih0raw[(size_t)(g * 128 + u2) * 257 + 256];
            }
#pragma unroll
            for (int mt = 0; mt < 2; ++mt) {
#pragma unroll
                for (int r = 0; r < 4; ++r) {
                    int m = mt * 16 + q * 4 + r;
                    int b = b0r + m;
                    float cond = (tt > 0) ? targets[b * 48 + tt - 1] : 0.0f;
                    float vi = acc[mt][0][r] + bias[0] + cond * wc[0];
                    float vf = acc[mt][1][r] + bias[1] + cond * wc[1];
                    float vg = acc[mt][2][r] + bias[2] + cond * wc[2];
                    float vo = acc[mt][3][r] + bias[3] + cond * wc[3];
                    uint_t lo = (uint_t)f2h_bits(vi) | ((uint_t)f2h_bits(vf) << 16);
                    uint_t hi = (uint_t)f2h_bits(vg) | ((uint_t)f2h_bits(vo) << 16);
                    size_t a = ((size_t)(b >> 4) * 48 + tt) * 4096 + (b & 15) * 256 + u2 * 2;
                    *(uint2*)(G1u + a) = make_uint2(lo, hi);
                }
            }
        }
        // publish: all stores visible, then count this block for time tt
        __threadfence();
        __syncthreads();
        if (tid == 0)
            __hip_atomic_fetch_add(&flags[tt * 32], 1u, __ATOMIC_RELEASE,
                                   __HIP_MEMORY_SCOPE_AGENT);
    } else {
        // ================= consumer: phaseB =================
        ushort_t* xA = (ushort_t*)smem;                       // 16*512 halves
        float (*ghead)[16] = (float(*)[16])(smem + 16384);    // 8*16 floats
        const int pb = blockIdx.x - 1536;
        const int r0 = pb * 16;
        const int u = wv * 16 + l16;

        for (int i = tid; i < 1024; i += 512) ((uint4*)xA)[i] = make_uint4(0, 0, 0, 0);

        // register-resident weights: Whh0 (16 frags) + L2-layer (32 frags)
        uintx4 B1w[4][4], B2[8][4];
#pragma unroll
        for (int kt = 0; kt < 4; ++kt)
#pragma unroll
            for (int g = 0; g < 4; ++g)
                B1w[kt][g] = *(const uintx4*)(N0m + ((size_t)((kt * 4 + q) * 512 + g * 128 + u)) * 8);
#pragma unroll
        for (int kt = 0; kt < 8; ++kt)
#pragma unroll
            for (int g = 0; g < 4; ++g)
                B2[kt][g] = *(const uintx4*)(N1m + ((size_t)((kt * 4 + q) * 512 + g * 128 + u)) * 8);

        const float bI = nb1[u], bF = nb1[128 + u], bG = nb1[256 + u], bO = nb1[384 + u];
        const float ob = outb[0];
        const float owf = outW[u];
        float c1[4] = {0, 0, 0, 0}, c2[4] = {0, 0, 0, 0};

        const uint_t* g1base = G1u + (size_t)pb * 48 * 4096;

        // wait for t=0 producers, then initial G1 load
        if (tid == 0)
            while (__hip_atomic_load(&flags[0], __ATOMIC_ACQUIRE, __HIP_MEMORY_SCOPE_AGENT) < 32u)
                __builtin_amdgcn_s_sleep(8);
        __syncthreads();

        uint2 g1c[4], g1n[4];
#pragma unroll
        for (int r = 0; r < 4; ++r)
            g1c[r] = *(const uint2*)(g1base + (q * 4 + r) * 256 + u * 2);

        const int kbW = u >> 3;
        const int jW = u & 7;

        for (int t = 0; t < 48; ++t) {
            const int cur = (t & 1) * 128;
            const int prv = cur ^ 128;
            const int tn = (t < 47) ? t + 1 : 47;

#pragma unroll
            for (int kt = 0; kt < 8; ++kt)
#pragma unroll
                for (int g = 0; g < 4; ++g) {
                    asm volatile("" : "+v"(B2[kt][g]));
                    if (kt < 4) asm volatile("" : "+v"(B1w[kt][g]));
                }

            // wait for producers of step t+1, then prefetch its G1
            if (tid == 0)
                while (__hip_atomic_load(&flags[tn * 32], __ATOMIC_ACQUIRE,
                                         __HIP_MEMORY_SCOPE_AGENT) < 32u)
                    __builtin_amdgcn_s_sleep(8);
            __syncthreads();
            {
                const uint_t* gp = g1base + (size_t)tn * 4096;
#pragma unroll
                for (int r = 0; r < 4; ++r)
                    g1n[r] = *(const uint2*)(gp + (q * 4 + r) * 256 + u * 2);
            }

            // L1 MFMA: gates = Whh0 @ h1(t-1); A from xA[prv], B from registers
            floatx4 acc[4] = {};
#pragma unroll
            for (int kt = 0; kt < 4; ++kt) {
                int kb = kt * 4 + q;
                int kbp = (kb ^ l16) & 15;
                half8_t a = *(const half8_t*)&xA[l16 * 512 + prv + kbp * 8];
#pragma unroll
                for (int g = 0; g < 4; ++g)
                    acc[g] = __builtin_amdgcn_mfma_f32_16x16x32_f16(a, h8x(B1w[kt][g]), acc[g], 0, 0, 0);
            }
            // E1: gate + write h1(t) into buf cur
#pragma unroll
            for (int r = 0; r < 4; ++r) {
                float gi = acc[0][r] + h2f_lo(g1c[r].x);
                float gf = acc[1][r] + h2f_hi(g1c[r].x);
                float gg = acc[2][r] + h2f_lo(g1c[r].y);
                float go = acc[3][r] + h2f_hi(g1c[r].y);
                c1[r] = sigm(gf) * c1[r] + sigm(gi) * tanhx(gg);
                float h1 = sigm(go) * tanhx(c1[r]);
                int m = q * 4 + r;
                xA[m * 512 + cur + (((kbW ^ m) & 15) << 3) + jW] = f2h_bits(h1);
            }
            // L2 MFMA part A: kt 4..7 = h2(t-1) from xA[256+prv]
            floatx4 acc2[4] = {};
#pragma unroll
            for (int kt = 4; kt < 8; ++kt) {
                int kbr = (kt & 3) * 4 + q;
                int kbp = (kbr ^ l16) & 15;
                half8_t a = *(const half8_t*)&xA[l16 * 512 + 256 + prv + kbp * 8];
#pragma unroll
                for (int g = 0; g < 4; ++g)
                    acc2[g] = __builtin_amdgcn_mfma_f32_16x16x32_f16(a, h8x(B2[kt][g]), acc2[g], 0, 0, 0);
            }
            __syncthreads();   // #1: h1(t) visible

            // L2 MFMA part B: kt 0..3 = h1(t) from xA[cur]
#pragma unroll
            for (int kt = 0; kt < 4; ++kt) {
                int kb = kt * 4 + q;
                int kbp = (kb ^ l16) & 15;
                half8_t a = *(const half8_t*)&xA[l16 * 512 + cur + kbp * 8];
#pragma unroll
                for (int g = 0; g < 4; ++g)
                    acc2[g] = __builtin_amdgcn_mfma_f32_16x16x32_f16(a, h8x(B2[kt][g]), acc2[g], 0, 0, 0);
            }
            // E2: gate + write h2(t) + head partial
            float p[4];
#pragma unroll
            for (int r = 0; r < 4; ++r) {
                float gi = acc2[0][r] + bI;
                float gf = acc2[1][r] + bF;
                float gg = acc2[2][r] + bG;
                float go = acc2[3][r] + bO;
                c2[r] = sigm(gf) * c2[r] + sigm(gi) * tanhx(gg);
                float h2 = sigm(go) * tanhx(c2[r]);
                int m = q * 4 + r;
                xA[m * 512 + 256 + cur + (((kbW ^ m) & 15) << 3) + jW] = f2h_bits(h2);
                p[r] = h2 * owf;
            }
#pragma unroll
            for (int mask = 1; mask < 16; mask <<= 1)
#pragma unroll
                for (int r = 0; r < 4; ++r) p[r] += __shfl_xor(p[r], mask, 64);
            if (l16 == 0) {
#pragma unroll
                for (int r = 0; r < 4; ++r) ghead[wv][q * 4 + r] = p[r];
            }
#pragma unroll
            for (int r = 0; r < 4; ++r) g1c[r] = g1n[r];
            __syncthreads();   // #2: h2(t) + ghead visible

            if (tid < 16) {
                float s = 0.0f;
#pragma unroll
                for (int w = 0; w < 8; ++w) s += ghead[w][tid];
                out[(r0 + tid) * 48 + t] = sigm(s + ob);
            }
        }
    }
}

extern "C" void kernel_launch(void* const* d_in, const int* in_sizes, int n_in,
                              void* d_out, int out_size, void* d_ws, size_t ws_size,
                              hipStream_t stream)
{
    const float* note  = (const float*)d_in[0];
    const float* targ  = (const float*)d_in[1];
    const float* tWih0 = (const float*)d_in[2];
    const float* tb0   = (const float*)d_in[4];
    const float* tWih1 = (const float*)d_in[5];
    const float* tb1   = (const float*)d_in[7];
    const float* nWih0 = (const float*)d_in[8];
    const float* nWhh0 = (const float*)d_in[9];
    const float* nb0   = (const float*)d_in[10];
    const float* nWih1 = (const float*)d_in[11];
    const float* nWhh1 = (const float*)d_in[12];
    const float* nb1   = (const float*)d_in[13];
    const float* outW  = (const float*)d_in[14];
    const float* outb  = (const float*)d_in[15];

    char* ws = (char*)d_ws;
    uint_t*   G1u   = (uint_t*)(ws);                // 50331648 B
    ushort_t* W0m   = (ushort_t*)(ws + 50331648);   //  98304 B
    ushort_t* W1m   = (ushort_t*)(ws + 50429952);   // 393216 B
    ushort_t* N0x   = (ushort_t*)(ws + 50823168);   // 262144 B
    ushort_t* N0m   = (ushort_t*)(ws + 51085312);   // 131072 B
    ushort_t* N1m   = (ushort_t*)(ws + 51216384);   // 262144 B
    uint_t*   flags = (uint_t*)(ws + 51478528);     //   6144 B

    // 573440 pack elems + 1536 flag slots = 574976 -> 2246 blocks
    packAll<<<2246, 256, 0, stream>>>(tWih0, tWih1, nWih0, nWhh0, nWih1, nWhh1,
                                      W0m, W1m, N0x, N0m, N1m, flags);
    mega<<<1600, 512, 36864, stream>>>(note, targ, W0m, tb0, W1m, tb1,
                                       N0x, nWih0, nb0, N0m, N1m, nb1,
                                       outW, outb, G1u, flags, (float*)d_out);
}